// Round 14
// baseline (114.876 us; speedup 1.0000x reference)
//
#include <hip/hip_runtime.h>

#define GBLOCK 256
#define BLOCK 256
#define TILE 128
#define LN2 0.69314718055994530942
#define K1F ((float)(-1.0 / (0.08 * 0.08 * LN2)))
#define W2F 0.0625f  // (0.02/0.08)^2 ; K2 = 16*K1

typedef __attribute__((ext_vector_type(8))) short short8;
typedef __attribute__((ext_vector_type(4))) float f32x4;

// ---- bf16 helpers (truncation split: x = hi + lo, |err| ~ 2^-17 rel) ----
__device__ __forceinline__ ushort btr(float x) {
    return (ushort)(__builtin_bit_cast(unsigned, x) >> 16);
}
__device__ __forceinline__ float bfl(ushort h) {
    return __builtin_bit_cast(float, ((unsigned)h) << 16);
}
__device__ __forceinline__ unsigned pk2(ushort a, ushort b) {
    return (unsigned)a | ((unsigned)b << 16);
}

// ws layout (bytes):
//   ttA ushort[2*Fpad*32]   (A-side tt fragments, K-rows of 32 bf16, top 16 zero)
//   ttB ushort[2*Fpad*32]
//   ndA ushort[2*Fpad*32]
//   ndB ushort[2*Fpad*32]
//   float partials[geomSlots + pairBlocks]
// Slot layouts (16 active K-slots per row):
//   ttA: ch0 ch1 ch2  ch0 ch1 ch2  cl0 cl1 cl2  s1h s1l ONE ONE 0 0 0
//   ttB: ch0 ch1 ch2  cl0 cl1 cl2  ch0 ch1 ch2  ONE ONE s1h s1l 0 0 0
//   ndA: mh0 mh1 mh2  mh0 mh1 mh2  ml0 ml1 ml2  0...
//   ndB: mh0 mh1 mh2  ml0 ml1 ml2  mh0 mh1 mh2  0...
// dot(ttA_i, ttB_j) = (gC_i)on(gC_j) + s1_i + s1_j = tt  (exp2 exponent)
// dot(ndA_i, ndB_j) = M_i . M_j = nd                     (M = N/sqrt(L))
// Padded faces are all-zero rows -> nd = 0 -> p = 0 -> contribution 0.

__global__ void geom_kernel(const float* __restrict__ vpred,
                            const float* __restrict__ vtarg,
                            const int* __restrict__ pf,
                            const int* __restrict__ tf,
                            ushort* __restrict__ ttA, ushort* __restrict__ ttB,
                            ushort* __restrict__ ndA, ushort* __restrict__ ndB,
                            float* __restrict__ partials, int F, int Fpad)
{
    int id = blockIdx.x * blockDim.x + threadIdx.x;
    float diag = 0.0f;
    if (id < 2 * Fpad) {
        int m = (id >= Fpad) ? 1 : 0;
        int f = id - m * Fpad;
        ushort chh[3] = {0, 0, 0}, cll[3] = {0, 0, 0};
        ushort mhh[3] = {0, 0, 0}, mll[3] = {0, 0, 0};
        ushort s1h = 0, s1l = 0, ONE = 0;
        if (f < F) {
            const float* Vv = m ? vtarg : vpred;
            const int* Fc = m ? tf : pf;
            int i0 = Fc[3 * f + 0];
            int i1 = Fc[3 * f + 1];
            int i2 = Fc[3 * f + 2];
            float ax = Vv[3 * i0 + 0], ay = Vv[3 * i0 + 1], az = Vv[3 * i0 + 2];
            float bx = Vv[3 * i1 + 0], by = Vv[3 * i1 + 1], bz = Vv[3 * i1 + 2];
            float cx = Vv[3 * i2 + 0], cy = Vv[3 * i2 + 1], cz = Vv[3 * i2 + 2];

            const float third = 1.0f / 3.0f;
            float Cx = (ax + bx + cx) * third;
            float Cy = (ay + by + cy) * third;
            float Cz = (az + bz + cz) * third;

            float e1x = bx - ax, e1y = by - ay, e1z = bz - az;
            float e2x = cx - ax, e2y = cy - ay, e2z = cz - az;
            float Nx = 0.5f * (e1y * e2z - e1z * e2y);
            float Ny = 0.5f * (e1z * e2x - e1x * e2z);
            float Nz = 0.5f * (e1x * e2y - e1y * e2x);
            float nn = Nx * Nx + Ny * Ny + Nz * Nz;
            float L = sqrtf(nn + 1e-12f);
            float invSL = 1.0f / sqrtf(L);

            const float g = sqrtf(-2.0f * K1F);
            float cc[3] = {g * Cx, g * Cy, g * Cz};
            float M[3] = {Nx * invSL, Ny * invSL, Nz * invSL};
            float s1 = K1F * (Cx * Cx + Cy * Cy + Cz * Cz);
#pragma unroll
            for (int d = 0; d < 3; ++d) {
                chh[d] = btr(cc[d]);
                cll[d] = btr(cc[d] - bfl(chh[d]));
                mhh[d] = btr(M[d]);
                mll[d] = btr(M[d] - bfl(mhh[d]));
            }
            s1h = btr(s1);
            s1l = btr(s1 - bfl(s1h));
            ONE = 0x3F80;  // bf16(1.0)

            float d = nn / L;  // analytic diagonal of symmetric terms
            diag = (1.0f + W2F) * d * d;
        }
        size_t base = (size_t)id * 32;  // row index = m*Fpad + f = id
        uint4 z4 = {0u, 0u, 0u, 0u};
        uint4 q0, q1;
        // ttA
        q0.x = pk2(chh[0], chh[1]); q0.y = pk2(chh[2], chh[0]);
        q0.z = pk2(chh[1], chh[2]); q0.w = pk2(cll[0], cll[1]);
        q1.x = pk2(cll[2], s1h);    q1.y = pk2(s1l, ONE);
        q1.z = pk2(ONE, 0);         q1.w = 0u;
        { uint4* p = (uint4*)(ttA + base); p[0] = q0; p[1] = q1; p[2] = z4; p[3] = z4; }
        // ttB
        q0.x = pk2(chh[0], chh[1]); q0.y = pk2(chh[2], cll[0]);
        q0.z = pk2(cll[1], cll[2]); q0.w = pk2(chh[0], chh[1]);
        q1.x = pk2(chh[2], ONE);    q1.y = pk2(ONE, s1h);
        q1.z = pk2(s1l, 0);         q1.w = 0u;
        { uint4* p = (uint4*)(ttB + base); p[0] = q0; p[1] = q1; p[2] = z4; p[3] = z4; }
        // ndA
        q0.x = pk2(mhh[0], mhh[1]); q0.y = pk2(mhh[2], mhh[0]);
        q0.z = pk2(mhh[1], mhh[2]); q0.w = pk2(mll[0], mll[1]);
        q1.x = pk2(mll[2], 0);      q1.y = 0u; q1.z = 0u; q1.w = 0u;
        { uint4* p = (uint4*)(ndA + base); p[0] = q0; p[1] = q1; p[2] = z4; p[3] = z4; }
        // ndB
        q0.x = pk2(mhh[0], mhh[1]); q0.y = pk2(mhh[2], mll[0]);
        q0.z = pk2(mll[1], mll[2]); q0.w = pk2(mhh[0], mhh[1]);
        q1.x = pk2(mhh[2], 0);      q1.y = 0u; q1.z = 0u; q1.w = 0u;
        { uint4* p = (uint4*)(ndB + base); p[0] = q0; p[1] = q1; p[2] = z4; p[3] = z4; }
    }
    for (int off = 32; off > 0; off >>= 1) diag += __shfl_down(diag, off, 64);
    int wid = threadIdx.x >> 6;
    if ((threadIdx.x & 63) == 0)
        partials[blockIdx.x * (GBLOCK / 64) + wid] = diag;  // plain store
}

// hot loop: 2 MFMAs per 16x16 subtile (tt-dot, nd-dot), then 4 outputs/lane:
// p = nd^2 (masked in diag-crossing tiles), e1 = exp2(tt), e2 = e1^16,
// acc += p*e1 / p*e2.  e1^16 via 4 squarings (full-rate muls, no 2nd trans op).
#define MLOOP(PRED)                                                          \
    for (int jt = 0; jt < 8; ++jt) {                                         \
        int rowB = jbase + jt * 16 + l15;                                    \
        short8 btt = *(const short8*)(tB + (size_t)rowB * 32 + koff);        \
        short8 bnd = *(const short8*)(nB + (size_t)rowB * 32 + koff);        \
        _Pragma("unroll")                                                    \
        for (int s = 0; s < 2; ++s) {                                        \
            f32x4 zz = {0.f, 0.f, 0.f, 0.f};                                 \
            f32x4 Dt = __builtin_amdgcn_mfma_f32_16x16x32_bf16(              \
                attF[s], btt, zz, 0, 0, 0);                                  \
            f32x4 Dn = __builtin_amdgcn_mfma_f32_16x16x32_bf16(              \
                andF[s], bnd, zz, 0, 0, 0);                                  \
            _Pragma("unroll")                                                \
            for (int r = 0; r < 4; ++r) {                                    \
                float nd = Dn[r];                                            \
                float p = nd * nd;                                           \
                if (PRED) {                                                  \
                    int ii = ibase + s * 16 + kg * 4 + r;                    \
                    int jj = jbase + jt * 16 + l15;                          \
                    p = (jj < ii) ? p : 0.0f;                                \
                }                                                            \
                float e1 = __builtin_amdgcn_exp2f(Dt[r]);                    \
                float u1 = e1 * e1;                                          \
                float u2 = u1 * u1;                                          \
                float u3 = u2 * u2;                                          \
                float e2 = u3 * u3;                                          \
                accA = fmaf(p, e1, accA);                                    \
                accB = fmaf(p, e2, accB);                                    \
            }                                                                \
        }                                                                    \
    }

__launch_bounds__(BLOCK, 8)
__global__ void pair_kernel(const ushort* __restrict__ ttA,
                            const ushort* __restrict__ ttB,
                            const ushort* __restrict__ ndA,
                            const ushort* __restrict__ ndB,
                            float* __restrict__ partials,
                            int Fpad, int nJC, int nSym)
{
    int bid = blockIdx.x;
    int t, ib, jc;
    bool pred = false;
    if (bid < 2 * nSym) {
        t = (bid < nSym) ? 0 : 1;
        int r = bid - t * nSym;
        int off = 0, ibf = 0;
        for (;;) {
            int c = ibf + 1;
            if (c > nJC) c = nJC;
            if (r < off + c) break;
            off += c;
            ibf++;
        }
        ib = ibf;
        jc = r - off;
        pred = (jc >= ib);  // diagonal tile: mask j < i
    } else {
        int r = bid - 2 * nSym;
        t = 2;
        ib = r / nJC;
        jc = r - ib * nJC;
    }
    float coeff = (t == 2) ? -2.0f : 2.0f;
    int X = (t == 1) ? 1 : 0;
    int Y = (t == 0) ? 0 : 1;

    int tid = threadIdx.x, wid = tid >> 6, lane = tid & 63;
    int l15 = lane & 15, kg = lane >> 4;
    int koff = kg * 8;

    const ushort* tA = ttA + (size_t)X * Fpad * 32;
    const ushort* nA = ndA + (size_t)X * Fpad * 32;
    const ushort* tB = ttB + (size_t)Y * Fpad * 32;
    const ushort* nB = ndB + (size_t)Y * Fpad * 32;

    int ibase = ib * TILE + wid * 32;
    int jbase = jc * TILE;
    int rowA0 = ibase + l15;

    short8 attF[2], andF[2];
    attF[0] = *(const short8*)(tA + (size_t)rowA0 * 32 + koff);
    attF[1] = *(const short8*)(tA + (size_t)(rowA0 + 16) * 32 + koff);
    andF[0] = *(const short8*)(nA + (size_t)rowA0 * 32 + koff);
    andF[1] = *(const short8*)(nA + (size_t)(rowA0 + 16) * 32 + koff);

    float accA = 0.0f, accB = 0.0f;

    if (!pred) {
        MLOOP(false)
    } else {
        MLOOP(true)
    }

    float ps = coeff * fmaf(W2F, accB, accA);
    for (int off = 32; off > 0; off >>= 1) ps += __shfl_down(ps, off, 64);
    __shared__ float wsum[BLOCK / 64];
    if (lane == 0) wsum[wid] = ps;
    __syncthreads();
    if (tid == 0)
        partials[bid] = wsum[0] + wsum[1] + wsum[2] + wsum[3];  // NO atomics
}

__global__ void final_reduce(const float* __restrict__ partials, int n,
                             float* __restrict__ out)
{
    float s = 0.0f;
    for (int i = threadIdx.x; i < n; i += GBLOCK) s += partials[i];
    for (int off = 32; off > 0; off >>= 1) s += __shfl_down(s, off, 64);
    __shared__ float wsum[GBLOCK / 64];
    int wid = threadIdx.x >> 6;
    if ((threadIdx.x & 63) == 0) wsum[wid] = s;
    __syncthreads();
    if (threadIdx.x == 0)
        out[0] = wsum[0] + wsum[1] + wsum[2] + wsum[3];
}

extern "C" void kernel_launch(void* const* d_in, const int* in_sizes, int n_in,
                              void* d_out, int out_size, void* d_ws, size_t ws_size,
                              hipStream_t stream) {
    const float* vpred = (const float*)d_in[0];
    const float* vtarg = (const float*)d_in[1];
    const int* pf = (const int*)d_in[2];
    const int* tf = (const int*)d_in[3];
    float* out = (float*)d_out;

    int F = in_sizes[2] / 3;  // B == 1
    int nIB = (F + TILE - 1) / TILE;
    int Fpad = nIB * TILE;
    int nJC = nIB;
    int nSym = nIB * (nIB + 1) / 2;
    int pairBlocks = 2 * nSym + nIB * nJC;

    size_t sz1 = (size_t)2 * Fpad * 32 * sizeof(ushort);
    char* w = (char*)d_ws;
    ushort* ttA = (ushort*)(w);
    ushort* ttB = (ushort*)(w + sz1);
    ushort* ndA = (ushort*)(w + 2 * sz1);
    ushort* ndB = (ushort*)(w + 3 * sz1);
    float* partials = (float*)(w + 4 * sz1);

    int gblocks = (2 * Fpad + GBLOCK - 1) / GBLOCK;
    int geomSlots = gblocks * (GBLOCK / 64);

    geom_kernel<<<gblocks, GBLOCK, 0, stream>>>(
        vpred, vtarg, pf, tf, ttA, ttB, ndA, ndB, partials, F, Fpad);

    pair_kernel<<<pairBlocks, BLOCK, 0, stream>>>(
        ttA, ttB, ndA, ndB, partials + geomSlots, Fpad, nJC, nSym);

    final_reduce<<<1, GBLOCK, 0, stream>>>(
        partials, geomSlots + pairBlocks, out);
}